// Round 5
// baseline (241.567 us; speedup 1.0000x reference)
//
#include <hip/hip_runtime.h>

typedef _Float16 f16_t;
typedef f16_t f16x8 __attribute__((ext_vector_type(8)));
typedef float f32x4 __attribute__((ext_vector_type(4)));

#define MFMA16(a,b,c) __builtin_amdgcn_mfma_f32_16x16x32_f16(a,b,c,0,0,0)

__device__ __forceinline__ f16x8 cvt8h(float4 a, float4 b){
  f16x8 r;
  r[0]=(f16_t)a.x; r[1]=(f16_t)a.y; r[2]=(f16_t)a.z; r[3]=(f16_t)a.w;
  r[4]=(f16_t)b.x; r[5]=(f16_t)b.y; r[6]=(f16_t)b.z; r[7]=(f16_t)b.w;
  return r;
}

// Stage rows x 256 f32 (row-major) -> LDS f16 [row][256], per-row XOR swizzle
// on 16B chunks: chunk' = chunk ^ (row&7). Row pitch 512B.
template<int NT>
__device__ __forceinline__ void stage_f16(const float* __restrict__ src,
                                          char* dst, int rows, int tid){
  const int nchunk = rows * 32;
  const float4* s4 = reinterpret_cast<const float4*>(src);
  for (int cid = tid; cid < nchunk; cid += NT){
    int r = cid >> 5, c = cid & 31;
    *reinterpret_cast<f16x8*>(dst + r*512 + ((c ^ (r&7))<<4)) = cvt8h(s4[cid*2], s4[cid*2+1]);
  }
}

__device__ __forceinline__ f16x8 ldsA(const char* buf, int row, int c16){
  return *reinterpret_cast<const f16x8*>(buf + row*512 + ((c16 ^ (row&7))<<4));
}

// 64x64 C tile at (m0,n0): C = A(lds f16) * W(global f32 -> f16)^T, K=256.
__device__ __forceinline__ void gemm64(f32x4 acc[4][4], const char* bufA,
    const float* __restrict__ W, int m0, int n0, int lo16, int hi4){
  #pragma unroll
  for (int kb = 0; kb < 8; ++kb){
    f16x8 bfr[4];
    #pragma unroll
    for (int nb = 0; nb < 4; ++nb){
      const float4* p = reinterpret_cast<const float4*>(W + ((n0 + nb*16 + lo16)<<8) + kb*32 + hi4*8);
      bfr[nb] = cvt8h(p[0], p[1]);
    }
    f16x8 af[4];
    #pragma unroll
    for (int mb = 0; mb < 4; ++mb) af[mb] = ldsA(bufA, m0 + mb*16 + lo16, kb*4 + hi4);
    #pragma unroll
    for (int mb = 0; mb < 4; ++mb){
      #pragma unroll
      for (int nb = 0; nb < 4; ++nb) acc[mb][nb] = MFMA16(af[mb], bfr[nb], acc[mb][nb]);
    }
  }
}

// ---------------------------------------------------------------------------
// k2_fused: per (expert e, 128-row batch tile):
//   h = x@W1[e]^T + b1 ; LN ; relu -> hr(f16 LDS) ; eo = hr@W2[e]^T + b2 ->
//   global f32 + f16 LDS ; k = eo@Wk^T + bk ; scores[b,hd,e] = q . k
// grid (2,256), block 512 = 8 waves (wm in {0,1} x wn/head in {0..3}).
// LDS 70.6KB + <=128 VGPR -> 2 blocks/CU resident.
// ---------------------------------------------------------------------------
__global__ __launch_bounds__(512, 4)
void k2_fused(const float* __restrict__ x, const float* __restrict__ W1,
              const float* __restrict__ b1, const float* __restrict__ g1,
              const float* __restrict__ bb1, const float* __restrict__ W2,
              const float* __restrict__ b2, const float* __restrict__ ipw,
              const float* __restrict__ ipb, const float* __restrict__ q,
              float* __restrict__ eo_out, float* __restrict__ scores)
{
  __shared__ char lds[70656];
  char* bufA = lds;                    // 64KB: x(f16) -> hr(f16) -> eo(f16)
  float* red = (float*)(lds + 65536);  // [128][8] = 4KB
  float* st  = (float*)(lds + 69632);  // [128][2] = 1KB

  const int e  = blockIdx.y;
  const int b0 = blockIdx.x * 128;
  const int tid = threadIdx.x;
  const int lane = tid & 63, wid = tid >> 6;
  const int lo16 = lane & 15, hi4 = lane >> 4;
  const int wm = wid >> 2, wn = wid & 3;
  const int m0 = wm * 64, n0 = wn * 64;

  stage_f16<512>(x + b0*256, bufA, 128, tid);
  __syncthreads();

  f32x4 acc[4][4];
  #pragma unroll
  for (int mb=0;mb<4;++mb){
    #pragma unroll
    for (int nb=0;nb<4;++nb) acc[mb][nb] = (f32x4)0.0f;
  }

  gemm64(acc, bufA, W1 + e*65536, m0, n0, lo16, hi4);

  float b1v[4], g1v[4], bbv[4];
  #pragma unroll
  for (int nb=0;nb<4;++nb){
    int c = n0 + nb*16 + lo16;
    b1v[nb] = b1[e*256 + c];
    g1v[nb] = g1[e*256 + c];
    bbv[nb] = bb1[e*256 + c];
  }
  #pragma unroll
  for (int mb=0;mb<4;++mb){
    #pragma unroll
    for (int nb=0;nb<4;++nb){
      #pragma unroll
      for (int r=0;r<4;++r) acc[mb][nb][r] += b1v[nb];
    }
  }

  // LN stats: per-row sum/sumsq across the 4 column-waves
  #pragma unroll
  for (int mb=0;mb<4;++mb){
    #pragma unroll
    for (int r=0;r<4;++r){
      float s=0.f, ss=0.f;
      #pragma unroll
      for (int nb=0;nb<4;++nb){ float v = acc[mb][nb][r]; s += v; ss += v*v; }
      #pragma unroll
      for (int m=1;m<16;m<<=1){ s += __shfl_xor(s, m, 64); ss += __shfl_xor(ss, m, 64); }
      if (lo16 == 0){
        int row = m0 + mb*16 + hi4*4 + r;
        red[row*8 + wn]     = s;
        red[row*8 + 4 + wn] = ss;
      }
    }
  }
  __syncthreads();   // also: all waves done reading x from bufA
  if (tid < 128){
    float s  = red[tid*8+0]+red[tid*8+1]+red[tid*8+2]+red[tid*8+3];
    float ss = red[tid*8+4]+red[tid*8+5]+red[tid*8+6]+red[tid*8+7];
    float mu = s * (1.f/256.f);
    float var = ss * (1.f/256.f) - mu*mu;
    st[tid*2]   = mu;
    st[tid*2+1] = rsqrtf(var + 1e-5f);
  }
  __syncthreads();

  // LN + relu -> hr (f16) back into bufA
  #pragma unroll
  for (int mb=0;mb<4;++mb){
    #pragma unroll
    for (int r=0;r<4;++r){
      int row = m0 + mb*16 + hi4*4 + r;
      float mu = st[row*2], rs = st[row*2+1];
      #pragma unroll
      for (int nb=0;nb<4;++nb){
        int c = n0 + nb*16 + lo16;
        float v = (acc[mb][nb][r] - mu) * rs * g1v[nb] + bbv[nb];
        v = fmaxf(v, 0.f);
        int off = row*512 + (((c>>3) ^ (row&7))<<4) + (c&7)*2;
        *reinterpret_cast<f16_t*>(bufA + off) = (f16_t)v;
      }
    }
  }
  __syncthreads();

  // GEMM2: eo = hr @ W2[e]^T + b2
  #pragma unroll
  for (int mb=0;mb<4;++mb){
    #pragma unroll
    for (int nb=0;nb<4;++nb) acc[mb][nb] = (f32x4)0.0f;
  }
  gemm64(acc, bufA, W2 + e*65536, m0, n0, lo16, hi4);

  float b2v[4];
  #pragma unroll
  for (int nb=0;nb<4;++nb) b2v[nb] = b2[e*256 + n0 + nb*16 + lo16];

  __syncthreads();  // all waves done reading hr before eo overwrites bufA

  #pragma unroll
  for (int mb=0;mb<4;++mb){
    #pragma unroll
    for (int r=0;r<4;++r){
      int row = m0 + mb*16 + hi4*4 + r;
      int b = b0 + row;
      #pragma unroll
      for (int nb=0;nb<4;++nb){
        int c = n0 + nb*16 + lo16;
        float v = acc[mb][nb][r] + b2v[nb];
        eo_out[(b*256 + e)*256 + c] = v;
        int off = row*512 + (((c>>3) ^ (row&7))<<4) + (c&7)*2;
        *reinterpret_cast<f16_t*>(bufA + off) = (f16_t)v;
      }
    }
  }
  __syncthreads();

  // GEMM3: k = eo @ Wk^T + bk ; scores = q . k  (wave column wn == head)
  #pragma unroll
  for (int mb=0;mb<4;++mb){
    #pragma unroll
    for (int nb=0;nb<4;++nb) acc[mb][nb] = (f32x4)0.0f;
  }
  gemm64(acc, bufA, ipw + 65536, m0, n0, lo16, hi4);

  float bkv[4];
  #pragma unroll
  for (int nb=0;nb<4;++nb) bkv[nb] = ipb[256 + n0 + nb*16 + lo16];

  #pragma unroll
  for (int mb=0;mb<4;++mb){
    #pragma unroll
    for (int r=0;r<4;++r){
      int row = m0 + mb*16 + hi4*4 + r;
      int b = b0 + row;
      float p = 0.f;
      #pragma unroll
      for (int nb=0;nb<4;++nb){
        int c = n0 + nb*16 + lo16;
        p += q[b*256 + c] * (acc[mb][nb][r] + bkv[nb]);
      }
      #pragma unroll
      for (int m=1;m<16;m<<=1) p += __shfl_xor(p, m, 64);
      if (lo16 == 0) scores[(b*4 + wn)*256 + e] = p;
    }
  }
}

// ---------------------------------------------------------------------------
// k_mini: out = act( maybeLN( (A @ W^T + bias) * scale ) ), 256x256x256, f16.
// grid 2, block 512.
// ---------------------------------------------------------------------------
__global__ __launch_bounds__(512, 4)
void k_mini(const float* __restrict__ A, const float* __restrict__ W,
            const float* __restrict__ bias, float scale, int do_ln,
            const float* __restrict__ g, const float* __restrict__ bb,
            int do_relu, float* __restrict__ out)
{
  __shared__ char lds[70656];
  char* bufA = lds;
  float* red = (float*)(lds + 65536);
  float* st  = (float*)(lds + 69632);

  const int b0 = blockIdx.x * 128;
  const int tid = threadIdx.x;
  const int lane = tid & 63, wid = tid >> 6;
  const int lo16 = lane & 15, hi4 = lane >> 4;
  const int wm = wid >> 2, wn = wid & 3;
  const int m0 = wm * 64, n0 = wn * 64;

  stage_f16<512>(A + b0*256, bufA, 128, tid);
  __syncthreads();

  f32x4 acc[4][4];
  #pragma unroll
  for (int mb=0;mb<4;++mb){
    #pragma unroll
    for (int nb=0;nb<4;++nb) acc[mb][nb] = (f32x4)0.0f;
  }
  gemm64(acc, bufA, W, m0, n0, lo16, hi4);

  float bv[4], gv[4], bbv[4];
  #pragma unroll
  for (int nb=0;nb<4;++nb){
    int c = n0 + nb*16 + lo16;
    bv[nb] = bias[c];
    gv[nb]  = do_ln ? g[c]  : 1.f;
    bbv[nb] = do_ln ? bb[c] : 0.f;
  }
  #pragma unroll
  for (int mb=0;mb<4;++mb){
    #pragma unroll
    for (int nb=0;nb<4;++nb){
      #pragma unroll
      for (int r=0;r<4;++r) acc[mb][nb][r] = (acc[mb][nb][r] + bv[nb]) * scale;
    }
  }

  if (do_ln){
    #pragma unroll
    for (int mb=0;mb<4;++mb){
      #pragma unroll
      for (int r=0;r<4;++r){
        float s=0.f, ss=0.f;
        #pragma unroll
        for (int nb=0;nb<4;++nb){ float v = acc[mb][nb][r]; s += v; ss += v*v; }
        #pragma unroll
        for (int m=1;m<16;m<<=1){ s += __shfl_xor(s, m, 64); ss += __shfl_xor(ss, m, 64); }
        if (lo16 == 0){
          int row = m0 + mb*16 + hi4*4 + r;
          red[row*8 + wn]     = s;
          red[row*8 + 4 + wn] = ss;
        }
      }
    }
    __syncthreads();
    if (tid < 128){
      float s  = red[tid*8+0]+red[tid*8+1]+red[tid*8+2]+red[tid*8+3];
      float ss = red[tid*8+4]+red[tid*8+5]+red[tid*8+6]+red[tid*8+7];
      float mu = s * (1.f/256.f);
      float var = ss * (1.f/256.f) - mu*mu;
      st[tid*2]   = mu;
      st[tid*2+1] = rsqrtf(var + 1e-5f);
    }
    __syncthreads();
  }

  #pragma unroll
  for (int mb=0;mb<4;++mb){
    #pragma unroll
    for (int r=0;r<4;++r){
      int row = m0 + mb*16 + hi4*4 + r;
      float mu = 0.f, rs = 1.f;
      if (do_ln){ mu = st[row*2]; rs = st[row*2+1]; }
      #pragma unroll
      for (int nb=0;nb<4;++nb){
        int c = n0 + nb*16 + lo16;
        float v = acc[mb][nb][r];
        if (do_ln) v = (v - mu) * rs * gv[nb] + bbv[nb];
        if (do_relu) v = fmaxf(v, 0.f);
        out[(b0 + row)*256 + c] = v;
      }
    }
  }
}

// ---------------------------------------------------------------------------
__global__ __launch_bounds__(256)
void k3_softmax(const float* __restrict__ scores, float* __restrict__ wts)
{
  const int b = blockIdx.x, t = threadIdx.x;
  const int wid = t >> 6, lane = t & 63;
  __shared__ float r4[4];
  float sc[4];
  #pragma unroll
  for (int n=0;n<4;++n) sc[n] = scores[(b*4 + n)*256 + t];
  float wsum = 0.f;
  for (int n=0;n<4;++n){
    float m = sc[n];
    #pragma unroll
    for (int k=1;k<64;k<<=1) m = fmaxf(m, __shfl_xor(m, k, 64));
    if (lane == 0) r4[wid] = m;
    __syncthreads();
    m = fmaxf(fmaxf(r4[0], r4[1]), fmaxf(r4[2], r4[3]));
    __syncthreads();
    float ex = __expf(sc[n] - m);
    float s = ex;
    #pragma unroll
    for (int k=1;k<64;k<<=1) s += __shfl_xor(s, k, 64);
    if (lane == 0) r4[wid] = s;
    __syncthreads();
    s = r4[0] + r4[1] + r4[2] + r4[3];
    __syncthreads();
    wsum += ex / s;
  }
  wts[b*256 + t] = wsum * 0.25f;
}

// ---------------------------------------------------------------------------
// k4a: reference's literal einsum 'beh,eh->bh' with weights shape (B,E):
//   combined[b,h] = sum_e eo[b,e,h] * wts_flat[e*256 + h]
// ---------------------------------------------------------------------------
__global__ __launch_bounds__(256)
void k4a_combined(const float* __restrict__ eo, const float* __restrict__ wts,
                  float* __restrict__ cmb)
{
  const int b = blockIdx.x, t = threadIdx.x;
  const float* p = eo + b*65536 + t;
  float c = 0.f;
  #pragma unroll 8
  for (int e2 = 0; e2 < 256; ++e2) c += p[e2*256] * wts[e2*256 + t];
  cmb[b*256 + t] = c;
}

extern "C" void kernel_launch(void* const* d_in, const int* in_sizes, int n_in,
                              void* d_out, int out_size, void* d_ws, size_t ws_size,
                              hipStream_t stream)
{
  const float* x    = (const float*)d_in[0];
  const float* te   = (const float*)d_in[1];
  const float* W1   = (const float*)d_in[2];
  const float* b1   = (const float*)d_in[3];
  const float* g1   = (const float*)d_in[4];
  const float* bb1  = (const float*)d_in[5];
  const float* W2   = (const float*)d_in[6];
  const float* b2   = (const float*)d_in[7];
  const float* ipw  = (const float*)d_in[8];
  const float* ipb  = (const float*)d_in[9];
  const float* cw   = (const float*)d_in[10];
  const float* cb   = (const float*)d_in[11];
  const float* cg   = (const float*)d_in[12];
  const float* cbt  = (const float*)d_in[13];

  float* out    = (float*)d_out;        // (256,256)
  float* wts    = out + 65536;          // (256,1,256)
  float* eo     = out + 131072;         // (256,256,256)
  float* ws     = (float*)d_ws;
  float* q      = ws;                   // 65536 f32
  float* scores = ws + 65536;           // 262144 f32 (B,4,E)
  float* cmb    = ws + 65536 + 262144;  // 65536 f32

  // q = (te @ Wq^T + bq) / 8
  k_mini<<<2, 512, 0, stream>>>(te, ipw, ipb, 0.125f, 0, nullptr, nullptr, 0, q);
  // per-expert fused chain -> eo (out) + scores
  k2_fused<<<dim3(2, 256), 512, 0, stream>>>(x, W1, b1, g1, bb1, W2, b2, ipw, ipb,
                                             q, eo, scores);
  // softmax over experts, mean over heads -> weights (out)
  k3_softmax<<<256, 256, 0, stream>>>(scores, wts);
  // combined[b,h] = sum_e eo[b,e,h] * wts[e,h]
  k4a_combined<<<256, 256, 0, stream>>>(eo, wts, cmb);
  // out = relu(LN(combined @ cw^T + cb))
  k_mini<<<2, 512, 0, stream>>>(cmb, cw, cb, 1.0f, 1, cg, cbt, 1, out);
}

// Round 6
// 153.598 us; speedup vs baseline: 1.5727x; 1.5727x over previous
//
#include <hip/hip_runtime.h>

typedef _Float16 f16_t;
typedef f16_t f16x8 __attribute__((ext_vector_type(8)));
typedef float f32x4 __attribute__((ext_vector_type(4)));

#define MFMA16(a,b,c) __builtin_amdgcn_mfma_f32_16x16x32_f16(a,b,c,0,0,0)

__device__ __forceinline__ f16x8 cvt8h(float4 a, float4 b){
  f16x8 r;
  r[0]=(f16_t)a.x; r[1]=(f16_t)a.y; r[2]=(f16_t)a.z; r[3]=(f16_t)a.w;
  r[4]=(f16_t)b.x; r[5]=(f16_t)b.y; r[6]=(f16_t)b.z; r[7]=(f16_t)b.w;
  return r;
}

// Stage rows x 256 f32 (row-major) -> LDS f16 [row][256], per-row XOR swizzle
// on 16B chunks: chunk' = chunk ^ (row&7). Row pitch 512B.
template<int NT>
__device__ __forceinline__ void stage_f16(const float* __restrict__ src,
                                          char* dst, int rows, int tid){
  const int nchunk = rows * 32;
  const float4* s4 = reinterpret_cast<const float4*>(src);
  for (int cid = tid; cid < nchunk; cid += NT){
    int r = cid >> 5, c = cid & 31;
    *reinterpret_cast<f16x8*>(dst + r*512 + ((c ^ (r&7))<<4)) = cvt8h(s4[cid*2], s4[cid*2+1]);
  }
}

__device__ __forceinline__ f16x8 ldsA(const char* buf, int row, int c16){
  return *reinterpret_cast<const f16x8*>(buf + row*512 + ((c16 ^ (row&7))<<4));
}

// 64x32 C tile: rows 0..63 from LDS, cols n0..n0+31 of W^T, K=256.
// f16 W path: the global load IS the MFMA B-fragment (no staging regs, no cvt).
__device__ __forceinline__ void gemm_w16(f32x4 acc[4][2], const char* bufA,
    const f16_t* __restrict__ Wh, int n0, int lo16, int hi4){
  #pragma unroll
  for (int kb = 0; kb < 8; ++kb){
    f16x8 bf[2];
    #pragma unroll
    for (int nb = 0; nb < 2; ++nb)
      bf[nb] = *reinterpret_cast<const f16x8*>(Wh + ((n0 + nb*16 + lo16)<<8) + kb*32 + hi4*8);
    f16x8 af[4];
    #pragma unroll
    for (int mb = 0; mb < 4; ++mb) af[mb] = ldsA(bufA, mb*16 + lo16, kb*4 + hi4);
    #pragma unroll
    for (int mb = 0; mb < 4; ++mb){
      #pragma unroll
      for (int nb = 0; nb < 2; ++nb) acc[mb][nb] = MFMA16(af[mb], bf[nb], acc[mb][nb]);
    }
  }
}

// f32-W streaming fallback (only used when ws_size can't hold f16 weights)
__device__ __forceinline__ void gemm_w32(f32x4 acc[4][2], const char* bufA,
    const float* __restrict__ W, int n0, int lo16, int hi4){
  #pragma unroll
  for (int kb = 0; kb < 8; ++kb){
    f16x8 bf[2];
    #pragma unroll
    for (int nb = 0; nb < 2; ++nb){
      const float4* p = reinterpret_cast<const float4*>(W + ((n0 + nb*16 + lo16)<<8) + kb*32 + hi4*8);
      bf[nb] = cvt8h(p[0], p[1]);
    }
    f16x8 af[4];
    #pragma unroll
    for (int mb = 0; mb < 4; ++mb) af[mb] = ldsA(bufA, mb*16 + lo16, kb*4 + hi4);
    #pragma unroll
    for (int mb = 0; mb < 4; ++mb){
      #pragma unroll
      for (int nb = 0; nb < 2; ++nb) acc[mb][nb] = MFMA16(af[mb], bf[nb], acc[mb][nb]);
    }
  }
}

// ---------------------------------------------------------------------------
// k0_cvt: one-shot f32 -> f16 conversion of W1, W2, Wk into d_ws.
// ---------------------------------------------------------------------------
__global__ __launch_bounds__(256)
void k0_cvt(const float* __restrict__ W1, const float* __restrict__ W2,
            const float* __restrict__ Wk, f16_t* __restrict__ w1h,
            f16_t* __restrict__ w2h, f16_t* __restrict__ wkh)
{
  const long long NG1 = 2097152, NG2 = 4194304, NGT = 4202496; // 8-elem groups
  for (long long gidx = (long long)blockIdx.x*256 + threadIdx.x; gidx < NGT;
       gidx += (long long)gridDim.x*256){
    const float4* s; f16_t* d; long long off;
    if (gidx < NG1){ s = (const float4*)W1; d = w1h; off = gidx; }
    else if (gidx < NG2){ s = (const float4*)W2; d = w2h; off = gidx - NG1; }
    else { s = (const float4*)Wk; d = wkh; off = gidx - NG2; }
    *reinterpret_cast<f16x8*>(d + off*8) = cvt8h(s[off*2], s[off*2+1]);
  }
}

// ---------------------------------------------------------------------------
// k2_fused: per (expert e, 64-row batch tile):
//   h = x@W1[e]^T + b1 ; LN ; relu -> hr(f16 LDS) ; eo = hr@W2[e]^T + b2 ->
//   global f32 + f16 LDS ; k = eo@Wk^T + bk ; scores[b,hd,e] = q . k
// grid (4,256), block 512 = 8 col-waves (wave wid owns cols wid*32..+32),
// acc[4][2] (32 regs) -> ~60 free VGPRs for load pipelining. LDS 36.9KB.
// ---------------------------------------------------------------------------
template<int W16>
__global__ __launch_bounds__(512, 4)
void k2_fused(const float* __restrict__ x, const void* __restrict__ W1v,
              const float* __restrict__ b1, const float* __restrict__ g1,
              const float* __restrict__ bb1, const void* __restrict__ W2v,
              const float* __restrict__ b2, const void* __restrict__ Wkv,
              const float* __restrict__ ipb, const float* __restrict__ q,
              float* __restrict__ eo_out, float* __restrict__ scores)
{
  __shared__ __align__(16) char lds[37376];
  char* bufA = lds;                    // 32KB: x(f16) -> hr(f16) -> eo(f16)
  float* red = (float*)(lds + 32768);  // [64][16] = 4KB
  float* st  = (float*)(lds + 36864);  // [64][2]  = 512B

  const int e  = blockIdx.y;
  const int b0 = blockIdx.x * 64;
  const int tid = threadIdx.x;
  const int lane = tid & 63, wid = tid >> 6;
  const int lo16 = lane & 15, hi4 = lane >> 4;
  const int n0 = wid * 32;

  stage_f16<512>(x + b0*256, bufA, 64, tid);
  __syncthreads();

  f32x4 acc[4][2];
  #pragma unroll
  for (int mb=0;mb<4;++mb){
    #pragma unroll
    for (int nb=0;nb<2;++nb) acc[mb][nb] = (f32x4)0.0f;
  }

  if (W16) gemm_w16(acc, bufA, (const f16_t*)W1v + e*65536, n0, lo16, hi4);
  else     gemm_w32(acc, bufA, (const float*)W1v + e*65536, n0, lo16, hi4);

  float b1v[2], g1v[2], bbv[2];
  #pragma unroll
  for (int nb=0;nb<2;++nb){
    int c = n0 + nb*16 + lo16;
    b1v[nb] = b1[e*256 + c];
    g1v[nb] = g1[e*256 + c];
    bbv[nb] = bb1[e*256 + c];
  }
  #pragma unroll
  for (int mb=0;mb<4;++mb){
    #pragma unroll
    for (int nb=0;nb<2;++nb){
      #pragma unroll
      for (int r=0;r<4;++r) acc[mb][nb][r] += b1v[nb];
    }
  }

  // LN stats: per-row sum/sumsq across the 8 column-waves
  #pragma unroll
  for (int mb=0;mb<4;++mb){
    #pragma unroll
    for (int r=0;r<4;++r){
      float s=0.f, ss=0.f;
      #pragma unroll
      for (int nb=0;nb<2;++nb){ float v = acc[mb][nb][r]; s += v; ss += v*v; }
      #pragma unroll
      for (int m=1;m<16;m<<=1){ s += __shfl_xor(s, m, 64); ss += __shfl_xor(ss, m, 64); }
      if (lo16 == 0){
        int row = mb*16 + hi4*4 + r;
        red[row*16 + wid]     = s;
        red[row*16 + 8 + wid] = ss;
      }
    }
  }
  __syncthreads();   // also: all waves done reading x from bufA
  if (tid < 64){
    float s  = 0.f, ss = 0.f;
    #pragma unroll
    for (int i=0;i<8;++i){ s += red[tid*16 + i]; ss += red[tid*16 + 8 + i]; }
    float mu = s * (1.f/256.f);
    float var = ss * (1.f/256.f) - mu*mu;
    st[tid*2]   = mu;
    st[tid*2+1] = rsqrtf(var + 1e-5f);
  }
  __syncthreads();

  // LN + relu -> hr (f16) back into bufA
  #pragma unroll
  for (int mb=0;mb<4;++mb){
    #pragma unroll
    for (int r=0;r<4;++r){
      int row = mb*16 + hi4*4 + r;
      float mu = st[row*2], rs = st[row*2+1];
      #pragma unroll
      for (int nb=0;nb<2;++nb){
        int c = n0 + nb*16 + lo16;
        float v = (acc[mb][nb][r] - mu) * rs * g1v[nb] + bbv[nb];
        v = fmaxf(v, 0.f);
        int off = row*512 + (((c>>3) ^ (row&7))<<4) + (c&7)*2;
        *reinterpret_cast<f16_t*>(bufA + off) = (f16_t)v;
      }
    }
  }
  __syncthreads();

  // GEMM2: eo = hr @ W2[e]^T + b2
  #pragma unroll
  for (int mb=0;mb<4;++mb){
    #pragma unroll
    for (int nb=0;nb<2;++nb) acc[mb][nb] = (f32x4)0.0f;
  }
  if (W16) gemm_w16(acc, bufA, (const f16_t*)W2v + e*65536, n0, lo16, hi4);
  else     gemm_w32(acc, bufA, (const float*)W2v + e*65536, n0, lo16, hi4);

  float b2v[2];
  #pragma unroll
  for (int nb=0;nb<2;++nb) b2v[nb] = b2[e*256 + n0 + nb*16 + lo16];

  __syncthreads();  // all waves done reading hr before eo overwrites bufA

  #pragma unroll
  for (int mb=0;mb<4;++mb){
    #pragma unroll
    for (int r=0;r<4;++r){
      int row = mb*16 + hi4*4 + r;
      int b = b0 + row;
      #pragma unroll
      for (int nb=0;nb<2;++nb){
        int c = n0 + nb*16 + lo16;
        float v = acc[mb][nb][r] + b2v[nb];
        eo_out[(b*256 + e)*256 + c] = v;
        int off = row*512 + (((c>>3) ^ (row&7))<<4) + (c&7)*2;
        *reinterpret_cast<f16_t*>(bufA + off) = (f16_t)v;
      }
    }
  }
  __syncthreads();

  // GEMM3: k = eo @ Wk^T + bk ; scores = q . k
  #pragma unroll
  for (int mb=0;mb<4;++mb){
    #pragma unroll
    for (int nb=0;nb<2;++nb) acc[mb][nb] = (f32x4)0.0f;
  }
  if (W16) gemm_w16(acc, bufA, (const f16_t*)Wkv, n0, lo16, hi4);
  else     gemm_w32(acc, bufA, (const float*)Wkv, n0, lo16, hi4);

  float bkv[2];
  #pragma unroll
  for (int nb=0;nb<2;++nb) bkv[nb] = ipb[256 + n0 + nb*16 + lo16];

  #pragma unroll
  for (int mb=0;mb<4;++mb){
    #pragma unroll
    for (int r=0;r<4;++r){
      int row = mb*16 + hi4*4 + r;
      int b = b0 + row;
      float p = 0.f;
      #pragma unroll
      for (int nb=0;nb<2;++nb){
        int c = n0 + nb*16 + lo16;
        p += q[b*256 + c] * (acc[mb][nb][r] + bkv[nb]);
      }
      #pragma unroll
      for (int m=1;m<16;m<<=1) p += __shfl_xor(p, m, 64);
      if (lo16 == 0) red[row*16 + wid] = p;   // partial over this wave's 32 cols
    }
  }
  __syncthreads();
  if (tid < 256){
    int row = tid >> 2, hd = tid & 3;
    float sc = red[row*16 + hd*2] + red[row*16 + hd*2 + 1];
    scores[((b0 + row)*4 + hd)*256 + e] = sc;
  }
}

// ---------------------------------------------------------------------------
// k_mini: out = act( maybeLN( (A @ W^T + bias) * scale ) ), 256x256x256, f16.
// grid 8 (32-row tiles), block 512 = 8 col-waves, acc[2][2].
// ---------------------------------------------------------------------------
__global__ __launch_bounds__(512, 4)
void k_mini(const float* __restrict__ A, const float* __restrict__ W,
            const float* __restrict__ bias, float scale, int do_ln,
            const float* __restrict__ g, const float* __restrict__ bb,
            int do_relu, float* __restrict__ out)
{
  __shared__ __align__(16) char lds[18688];
  char* bufA = lds;                    // 16KB: A rows (f16)
  float* red = (float*)(lds + 16384);  // [32][16] = 2KB
  float* st  = (float*)(lds + 18432);  // [32][2]  = 256B

  const int b0 = blockIdx.x * 32;
  const int tid = threadIdx.x;
  const int lane = tid & 63, wid = tid >> 6;
  const int lo16 = lane & 15, hi4 = lane >> 4;
  const int n0 = wid * 32;

  stage_f16<512>(A + b0*256, bufA, 32, tid);
  __syncthreads();

  f32x4 acc[2][2];
  #pragma unroll
  for (int mb=0;mb<2;++mb){
    #pragma unroll
    for (int nb=0;nb<2;++nb) acc[mb][nb] = (f32x4)0.0f;
  }
  #pragma unroll
  for (int kb = 0; kb < 8; ++kb){
    f16x8 bf[2];
    #pragma unroll
    for (int nb = 0; nb < 2; ++nb){
      const float4* p = reinterpret_cast<const float4*>(W + ((n0 + nb*16 + lo16)<<8) + kb*32 + hi4*8);
      bf[nb] = cvt8h(p[0], p[1]);
    }
    f16x8 af[2];
    #pragma unroll
    for (int mb = 0; mb < 2; ++mb) af[mb] = ldsA(bufA, mb*16 + lo16, kb*4 + hi4);
    #pragma unroll
    for (int mb = 0; mb < 2; ++mb){
      #pragma unroll
      for (int nb = 0; nb < 2; ++nb) acc[mb][nb] = MFMA16(af[mb], bf[nb], acc[mb][nb]);
    }
  }

  float bv[2], gv[2], bbv[2];
  #pragma unroll
  for (int nb=0;nb<2;++nb){
    int c = n0 + nb*16 + lo16;
    bv[nb]  = bias[c];
    gv[nb]  = do_ln ? g[c]  : 1.f;
    bbv[nb] = do_ln ? bb[c] : 0.f;
  }
  #pragma unroll
  for (int mb=0;mb<2;++mb){
    #pragma unroll
    for (int nb=0;nb<2;++nb){
      #pragma unroll
      for (int r=0;r<4;++r) acc[mb][nb][r] = (acc[mb][nb][r] + bv[nb]) * scale;
    }
  }

  if (do_ln){
    #pragma unroll
    for (int mb=0;mb<2;++mb){
      #pragma unroll
      for (int r=0;r<4;++r){
        float s=0.f, ss=0.f;
        #pragma unroll
        for (int nb=0;nb<2;++nb){ float v = acc[mb][nb][r]; s += v; ss += v*v; }
        #pragma unroll
        for (int m=1;m<16;m<<=1){ s += __shfl_xor(s, m, 64); ss += __shfl_xor(ss, m, 64); }
        if (lo16 == 0){
          int row = mb*16 + hi4*4 + r;
          red[row*16 + wid]     = s;
          red[row*16 + 8 + wid] = ss;
        }
      }
    }
    __syncthreads();
    if (tid < 32){
      float s = 0.f, ss = 0.f;
      #pragma unroll
      for (int i=0;i<8;++i){ s += red[tid*16 + i]; ss += red[tid*16 + 8 + i]; }
      float mu = s * (1.f/256.f);
      float var = ss * (1.f/256.f) - mu*mu;
      st[tid*2]   = mu;
      st[tid*2+1] = rsqrtf(var + 1e-5f);
    }
    __syncthreads();
  }

  #pragma unroll
  for (int mb=0;mb<2;++mb){
    #pragma unroll
    for (int r=0;r<4;++r){
      int row = mb*16 + hi4*4 + r;
      float mu = 0.f, rs = 1.f;
      if (do_ln){ mu = st[row*2]; rs = st[row*2+1]; }
      #pragma unroll
      for (int nb=0;nb<2;++nb){
        int c = n0 + nb*16 + lo16;
        float v = acc[mb][nb][r];
        if (do_ln) v = (v - mu) * rs * gv[nb] + bbv[nb];
        if (do_relu) v = fmaxf(v, 0.f);
        out[(b0 + row)*256 + c] = v;
      }
    }
  }
}

// ---------------------------------------------------------------------------
__global__ __launch_bounds__(256)
void k3_softmax(const float* __restrict__ scores, float* __restrict__ wts)
{
  const int b = blockIdx.x, t = threadIdx.x;
  const int wid = t >> 6, lane = t & 63;
  __shared__ float r4[4];
  float sc[4];
  #pragma unroll
  for (int n=0;n<4;++n) sc[n] = scores[(b*4 + n)*256 + t];
  float wsum = 0.f;
  for (int n=0;n<4;++n){
    float m = sc[n];
    #pragma unroll
    for (int k=1;k<64;k<<=1) m = fmaxf(m, __shfl_xor(m, k, 64));
    if (lane == 0) r4[wid] = m;
    __syncthreads();
    m = fmaxf(fmaxf(r4[0], r4[1]), fmaxf(r4[2], r4[3]));
    __syncthreads();
    float ex = __expf(sc[n] - m);
    float s = ex;
    #pragma unroll
    for (int k=1;k<64;k<<=1) s += __shfl_xor(s, k, 64);
    if (lane == 0) r4[wid] = s;
    __syncthreads();
    s = r4[0] + r4[1] + r4[2] + r4[3];
    __syncthreads();
    wsum += ex / s;
  }
  wts[b*256 + t] = wsum * 0.25f;
}

// ---------------------------------------------------------------------------
// k4a: reference's literal einsum 'beh,eh->bh' with weights shape (B,E):
//   combined[b,h] = sum_e eo[b,e,h] * wts_flat[e*256 + h]
// block 1024: 4 e-chunks in parallel (4x MLP), LDS reduce.
// ---------------------------------------------------------------------------
__global__ __launch_bounds__(1024)
void k4a_combined(const float* __restrict__ eo, const float* __restrict__ wts,
                  float* __restrict__ cmb)
{
  __shared__ float part[1024];
  const int b = blockIdx.x, t = threadIdx.x;
  const int c = t >> 8, h = t & 255;
  const float* p = eo + b*65536 + h;
  float s = 0.f;
  #pragma unroll 8
  for (int i = 0; i < 64; ++i){
    int e2 = c*64 + i;
    s += p[e2*256] * wts[e2*256 + h];
  }
  part[t] = s;
  __syncthreads();
  if (t < 256) cmb[b*256 + t] = part[t] + part[t+256] + part[t+512] + part[t+768];
}

extern "C" void kernel_launch(void* const* d_in, const int* in_sizes, int n_in,
                              void* d_out, int out_size, void* d_ws, size_t ws_size,
                              hipStream_t stream)
{
  const float* x    = (const float*)d_in[0];
  const float* te   = (const float*)d_in[1];
  const float* W1   = (const float*)d_in[2];
  const float* b1   = (const float*)d_in[3];
  const float* g1   = (const float*)d_in[4];
  const float* bb1  = (const float*)d_in[5];
  const float* W2   = (const float*)d_in[6];
  const float* b2   = (const float*)d_in[7];
  const float* ipw  = (const float*)d_in[8];
  const float* ipb  = (const float*)d_in[9];
  const float* cw   = (const float*)d_in[10];
  const float* cb   = (const float*)d_in[11];
  const float* cg   = (const float*)d_in[12];
  const float* cbt  = (const float*)d_in[13];

  float* out    = (float*)d_out;        // (256,256)
  float* wts    = out + 65536;          // (256,1,256)
  float* eo     = out + 131072;         // (256,256,256)

  // ws layout (f16-W path): w1h | w2h | wkh | q | scores | cmb
  const size_t F16_BYTES = 2ull*(16777216ull*2 + 65536);   // 67239936
  const size_t NEED = F16_BYTES + 4ull*(65536 + 262144 + 65536); // 68812800
  const bool f16w = ws_size >= NEED;

  f16_t* w1h = (f16_t*)d_ws;
  f16_t* w2h = w1h + 16777216;
  f16_t* wkh = w2h + 16777216;
  float* fbase = f16w ? (float*)((char*)d_ws + F16_BYTES) : (float*)d_ws;
  float* q      = fbase;
  float* scores = q + 65536;
  float* cmb    = scores + 262144;

  // q = (te @ Wq^T + bq) / 8
  k_mini<<<8, 512, 0, stream>>>(te, ipw, ipb, 0.125f, 0, nullptr, nullptr, 0, q);

  if (f16w){
    k0_cvt<<<2048, 256, 0, stream>>>(W1, W2, ipw + 65536, w1h, w2h, wkh);
    k2_fused<1><<<dim3(4, 256), 512, 0, stream>>>(x, w1h, b1, g1, bb1, w2h, b2,
                                                  wkh, ipb, q, eo, scores);
  } else {
    k2_fused<0><<<dim3(4, 256), 512, 0, stream>>>(x, W1, b1, g1, bb1, W2, b2,
                                                  ipw + 65536, ipb, q, eo, scores);
  }

  // softmax over experts, mean over heads -> weights (out)
  k3_softmax<<<256, 256, 0, stream>>>(scores, wts);
  // combined[b,h] = sum_e eo[b,e,h] * wts[e,h]
  k4a_combined<<<256, 1024, 0, stream>>>(eo, wts, cmb);
  // out = relu(LN(combined @ cw^T + cb))
  k_mini<<<8, 512, 0, stream>>>(cmb, cw, cb, 1.0f, 1, cg, cbt, 1, out);
}

// Round 7
// 148.343 us; speedup vs baseline: 1.6284x; 1.0354x over previous
//
#include <hip/hip_runtime.h>

typedef _Float16 f16_t;
typedef f16_t f16x8 __attribute__((ext_vector_type(8)));
typedef float f32x4 __attribute__((ext_vector_type(4)));

#define MFMA16(a,b,c) __builtin_amdgcn_mfma_f32_16x16x32_f16(a,b,c,0,0,0)

__device__ __forceinline__ f16x8 cvt8h(float4 a, float4 b){
  f16x8 r;
  r[0]=(f16_t)a.x; r[1]=(f16_t)a.y; r[2]=(f16_t)a.z; r[3]=(f16_t)a.w;
  r[4]=(f16_t)b.x; r[5]=(f16_t)b.y; r[6]=(f16_t)b.z; r[7]=(f16_t)b.w;
  return r;
}

// Stage rows x 256 f32 (row-major) -> LDS f16 [row][256], per-row XOR swizzle
// on 16B chunks: chunk' = chunk ^ (row&7). Row pitch 512B.
template<int NT>
__device__ __forceinline__ void stage_f16(const float* __restrict__ src,
                                          char* dst, int rows, int tid){
  const int nchunk = rows * 32;
  const float4* s4 = reinterpret_cast<const float4*>(src);
  for (int cid = tid; cid < nchunk; cid += NT){
    int r = cid >> 5, c = cid & 31;
    *reinterpret_cast<f16x8*>(dst + r*512 + ((c ^ (r&7))<<4)) = cvt8h(s4[cid*2], s4[cid*2+1]);
  }
}

__device__ __forceinline__ f16x8 ldsA(const char* buf, int row, int c16){
  return *reinterpret_cast<const f16x8*>(buf + row*512 + ((c16 ^ (row&7))<<4));
}

// 64x32 C tile: rows 0..63 from LDS, cols n0..n0+31 of W^T, K=256, f16 W.
// ALL 16 B-fragment loads issued upfront (64 VGPRs in flight) so the global
// load latency is covered by the load batch itself, not by other waves.
__device__ __forceinline__ void gemm_w16(f32x4 acc[4][2], const char* bufA,
    const f16_t* __restrict__ Wh, int n0, int lo16, int hi4){
  f16x8 bf[8][2];
  #pragma unroll
  for (int kb = 0; kb < 8; ++kb){
    #pragma unroll
    for (int nb = 0; nb < 2; ++nb)
      bf[kb][nb] = *reinterpret_cast<const f16x8*>(Wh + ((n0 + nb*16 + lo16)<<8) + kb*32 + hi4*8);
  }
  #pragma unroll
  for (int kb = 0; kb < 8; ++kb){
    #pragma unroll
    for (int mb = 0; mb < 4; ++mb){
      f16x8 af = ldsA(bufA, mb*16 + lo16, kb*4 + hi4);
      acc[mb][0] = MFMA16(af, bf[kb][0], acc[mb][0]);
      acc[mb][1] = MFMA16(af, bf[kb][1], acc[mb][1]);
    }
  }
}

// f32-W streaming fallback (only used when ws_size can't hold f16 weights)
__device__ __forceinline__ void gemm_w32(f32x4 acc[4][2], const char* bufA,
    const float* __restrict__ W, int n0, int lo16, int hi4){
  #pragma unroll
  for (int kb = 0; kb < 8; ++kb){
    f16x8 bf[2];
    #pragma unroll
    for (int nb = 0; nb < 2; ++nb){
      const float4* p = reinterpret_cast<const float4*>(W + ((n0 + nb*16 + lo16)<<8) + kb*32 + hi4*8);
      bf[nb] = cvt8h(p[0], p[1]);
    }
    #pragma unroll
    for (int mb = 0; mb < 4; ++mb){
      f16x8 af = ldsA(bufA, mb*16 + lo16, kb*4 + hi4);
      acc[mb][0] = MFMA16(af, bf[0], acc[mb][0]);
      acc[mb][1] = MFMA16(af, bf[1], acc[mb][1]);
    }
  }
}

// ---------------------------------------------------------------------------
// k0_cvt: one-shot f32 -> f16 conversion of W1, W2, Wk into d_ws.
// ---------------------------------------------------------------------------
__global__ __launch_bounds__(256)
void k0_cvt(const float* __restrict__ W1, const float* __restrict__ W2,
            const float* __restrict__ Wk, f16_t* __restrict__ w1h,
            f16_t* __restrict__ w2h, f16_t* __restrict__ wkh)
{
  const long long NG1 = 2097152, NG2 = 4194304, NGT = 4202496; // 8-elem groups
  for (long long gidx = (long long)blockIdx.x*256 + threadIdx.x; gidx < NGT;
       gidx += (long long)gridDim.x*256){
    const float4* s; f16_t* d; long long off;
    if (gidx < NG1){ s = (const float4*)W1; d = w1h; off = gidx; }
    else if (gidx < NG2){ s = (const float4*)W2; d = w2h; off = gidx - NG1; }
    else { s = (const float4*)Wk; d = wkh; off = gidx - NG2; }
    *reinterpret_cast<f16x8*>(d + off*8) = cvt8h(s[off*2], s[off*2+1]);
  }
}

// ---------------------------------------------------------------------------
// k2_fused: per (expert e, 64-row batch tile):
//   h = x@W1[e]^T + b1 ; LN ; relu -> hr(f16 LDS) ; eo = hr@W2[e]^T + b2 ->
//   global f32 + f16 LDS ; k = eo@Wk^T + bk ; scores[b,hd,e] = q . k
// grid 1024 (XCD-swizzled), block 512 = 8 col-waves (wave wid owns 32 cols).
// Swizzle: xcd = l&7, e = xcd*32 + (l>>5), tile = (l>>3)&3 -> the 4 tiles of
// one expert land on the SAME XCD (ids 8 apart) => W1[e]/W2[e] hit L2 3/4x.
// ---------------------------------------------------------------------------
template<int W16>
__global__ __launch_bounds__(512, 4)
void k2_fused(const float* __restrict__ x, const void* __restrict__ W1v,
              const float* __restrict__ b1, const float* __restrict__ g1,
              const float* __restrict__ bb1, const void* __restrict__ W2v,
              const float* __restrict__ b2, const void* __restrict__ Wkv,
              const float* __restrict__ ipb, const float* __restrict__ q,
              float* __restrict__ eo_out, float* __restrict__ scores)
{
  __shared__ __align__(16) char lds[37376];
  char* bufA = lds;                    // 32KB: x(f16) -> hr(f16) -> eo(f16)
  float* red = (float*)(lds + 32768);  // [64][16] = 4KB
  float* st  = (float*)(lds + 36864);  // [64][2]  = 512B

  const int l = blockIdx.x;
  const int e    = (l & 7) * 32 + (l >> 5);
  const int b0   = ((l >> 3) & 3) * 64;
  const int tid = threadIdx.x;
  const int lane = tid & 63, wid = tid >> 6;
  const int lo16 = lane & 15, hi4 = lane >> 4;
  const int n0 = wid * 32;

  stage_f16<512>(x + b0*256, bufA, 64, tid);
  __syncthreads();

  f32x4 acc[4][2];
  #pragma unroll
  for (int mb=0;mb<4;++mb){
    #pragma unroll
    for (int nb=0;nb<2;++nb) acc[mb][nb] = (f32x4)0.0f;
  }

  if (W16) gemm_w16(acc, bufA, (const f16_t*)W1v + e*65536, n0, lo16, hi4);
  else     gemm_w32(acc, bufA, (const float*)W1v + e*65536, n0, lo16, hi4);

  float b1v[2], g1v[2], bbv[2];
  #pragma unroll
  for (int nb=0;nb<2;++nb){
    int c = n0 + nb*16 + lo16;
    b1v[nb] = b1[e*256 + c];
    g1v[nb] = g1[e*256 + c];
    bbv[nb] = bb1[e*256 + c];
  }
  #pragma unroll
  for (int mb=0;mb<4;++mb){
    #pragma unroll
    for (int nb=0;nb<2;++nb){
      #pragma unroll
      for (int r=0;r<4;++r) acc[mb][nb][r] += b1v[nb];
    }
  }

  // LN stats: per-row sum/sumsq across the 8 column-waves
  #pragma unroll
  for (int mb=0;mb<4;++mb){
    #pragma unroll
    for (int r=0;r<4;++r){
      float s=0.f, ss=0.f;
      #pragma unroll
      for (int nb=0;nb<2;++nb){ float v = acc[mb][nb][r]; s += v; ss += v*v; }
      #pragma unroll
      for (int m=1;m<16;m<<=1){ s += __shfl_xor(s, m, 64); ss += __shfl_xor(ss, m, 64); }
      if (lo16 == 0){
        int row = mb*16 + hi4*4 + r;
        red[row*16 + wid]     = s;
        red[row*16 + 8 + wid] = ss;
      }
    }
  }
  __syncthreads();   // also: all waves done reading x from bufA
  if (tid < 64){
    float s  = 0.f, ss = 0.f;
    #pragma unroll
    for (int i=0;i<8;++i){ s += red[tid*16 + i]; ss += red[tid*16 + 8 + i]; }
    float mu = s * (1.f/256.f);
    float var = ss * (1.f/256.f) - mu*mu;
    st[tid*2]   = mu;
    st[tid*2+1] = rsqrtf(var + 1e-5f);
  }
  __syncthreads();

  // LN + relu -> hr (f16) back into bufA
  #pragma unroll
  for (int mb=0;mb<4;++mb){
    #pragma unroll
    for (int r=0;r<4;++r){
      int row = mb*16 + hi4*4 + r;
      float mu = st[row*2], rs = st[row*2+1];
      #pragma unroll
      for (int nb=0;nb<2;++nb){
        int c = n0 + nb*16 + lo16;
        float v = (acc[mb][nb][r] - mu) * rs * g1v[nb] + bbv[nb];
        v = fmaxf(v, 0.f);
        int off = row*512 + (((c>>3) ^ (row&7))<<4) + (c&7)*2;
        *reinterpret_cast<f16_t*>(bufA + off) = (f16_t)v;
      }
    }
  }
  __syncthreads();

  // GEMM2: eo = hr @ W2[e]^T + b2
  #pragma unroll
  for (int mb=0;mb<4;++mb){
    #pragma unroll
    for (int nb=0;nb<2;++nb) acc[mb][nb] = (f32x4)0.0f;
  }
  if (W16) gemm_w16(acc, bufA, (const f16_t*)W2v + e*65536, n0, lo16, hi4);
  else     gemm_w32(acc, bufA, (const float*)W2v + e*65536, n0, lo16, hi4);

  float b2v[2];
  #pragma unroll
  for (int nb=0;nb<2;++nb) b2v[nb] = b2[e*256 + n0 + nb*16 + lo16];

  __syncthreads();  // all waves done reading hr before eo overwrites bufA

  #pragma unroll
  for (int mb=0;mb<4;++mb){
    #pragma unroll
    for (int r=0;r<4;++r){
      int row = mb*16 + hi4*4 + r;
      int b = b0 + row;
      #pragma unroll
      for (int nb=0;nb<2;++nb){
        int c = n0 + nb*16 + lo16;
        float v = acc[mb][nb][r] + b2v[nb];
        eo_out[(b*256 + e)*256 + c] = v;
        int off = row*512 + (((c>>3) ^ (row&7))<<4) + (c&7)*2;
        *reinterpret_cast<f16_t*>(bufA + off) = (f16_t)v;
      }
    }
  }
  __syncthreads();

  // GEMM3: k = eo @ Wk^T + bk ; scores = q . k
  #pragma unroll
  for (int mb=0;mb<4;++mb){
    #pragma unroll
    for (int nb=0;nb<2;++nb) acc[mb][nb] = (f32x4)0.0f;
  }
  if (W16) gemm_w16(acc, bufA, (const f16_t*)Wkv, n0, lo16, hi4);
  else     gemm_w32(acc, bufA, (const float*)Wkv, n0, lo16, hi4);

  float bkv[2];
  #pragma unroll
  for (int nb=0;nb<2;++nb) bkv[nb] = ipb[256 + n0 + nb*16 + lo16];

  #pragma unroll
  for (int mb=0;mb<4;++mb){
    #pragma unroll
    for (int r=0;r<4;++r){
      int row = mb*16 + hi4*4 + r;
      int b = b0 + row;
      float p = 0.f;
      #pragma unroll
      for (int nb=0;nb<2;++nb){
        int c = n0 + nb*16 + lo16;
        p += q[b*256 + c] * (acc[mb][nb][r] + bkv[nb]);
      }
      #pragma unroll
      for (int m=1;m<16;m<<=1) p += __shfl_xor(p, m, 64);
      if (lo16 == 0) red[row*16 + wid] = p;   // partial over this wave's 32 cols
    }
  }
  __syncthreads();
  if (tid < 256){
    int row = tid >> 2, hd = tid & 3;
    float sc = red[row*16 + hd*2] + red[row*16 + hd*2 + 1];
    scores[((b0 + row)*4 + hd)*256 + e] = sc;
  }
}

// ---------------------------------------------------------------------------
// k_mini: out = act( maybeLN( (A @ W^T + bias) * scale ) ), 256x256x256, f16.
// grid 8 (32-row tiles), block 512 = 8 col-waves, acc[2][2].
// ---------------------------------------------------------------------------
__global__ __launch_bounds__(512, 4)
void k_mini(const float* __restrict__ A, const float* __restrict__ W,
            const float* __restrict__ bias, float scale, int do_ln,
            const float* __restrict__ g, const float* __restrict__ bb,
            int do_relu, float* __restrict__ out)
{
  __shared__ __align__(16) char lds[18688];
  char* bufA = lds;                    // 16KB: A rows (f16)
  float* red = (float*)(lds + 16384);  // [32][16] = 2KB
  float* st  = (float*)(lds + 18432);  // [32][2]  = 256B

  const int b0 = blockIdx.x * 32;
  const int tid = threadIdx.x;
  const int lane = tid & 63, wid = tid >> 6;
  const int lo16 = lane & 15, hi4 = lane >> 4;
  const int n0 = wid * 32;

  stage_f16<512>(A + b0*256, bufA, 32, tid);
  __syncthreads();

  f32x4 acc[2][2];
  #pragma unroll
  for (int mb=0;mb<2;++mb){
    #pragma unroll
    for (int nb=0;nb<2;++nb) acc[mb][nb] = (f32x4)0.0f;
  }
  #pragma unroll
  for (int kb = 0; kb < 8; ++kb){
    f16x8 bf[2];
    #pragma unroll
    for (int nb = 0; nb < 2; ++nb){
      const float4* p = reinterpret_cast<const float4*>(W + ((n0 + nb*16 + lo16)<<8) + kb*32 + hi4*8);
      bf[nb] = cvt8h(p[0], p[1]);
    }
    #pragma unroll
    for (int mb = 0; mb < 2; ++mb){
      f16x8 af = ldsA(bufA, mb*16 + lo16, kb*4 + hi4);
      acc[mb][0] = MFMA16(af, bf[0], acc[mb][0]);
      acc[mb][1] = MFMA16(af, bf[1], acc[mb][1]);
    }
  }

  float bv[2], gv[2], bbv[2];
  #pragma unroll
  for (int nb=0;nb<2;++nb){
    int c = n0 + nb*16 + lo16;
    bv[nb]  = bias[c];
    gv[nb]  = do_ln ? g[c]  : 1.f;
    bbv[nb] = do_ln ? bb[c] : 0.f;
  }
  #pragma unroll
  for (int mb=0;mb<2;++mb){
    #pragma unroll
    for (int nb=0;nb<2;++nb){
      #pragma unroll
      for (int r=0;r<4;++r) acc[mb][nb][r] = (acc[mb][nb][r] + bv[nb]) * scale;
    }
  }

  if (do_ln){
    #pragma unroll
    for (int mb=0;mb<2;++mb){
      #pragma unroll
      for (int r=0;r<4;++r){
        float s=0.f, ss=0.f;
        #pragma unroll
        for (int nb=0;nb<2;++nb){ float v = acc[mb][nb][r]; s += v; ss += v*v; }
        #pragma unroll
        for (int m=1;m<16;m<<=1){ s += __shfl_xor(s, m, 64); ss += __shfl_xor(ss, m, 64); }
        if (lo16 == 0){
          int row = mb*16 + hi4*4 + r;
          red[row*16 + wid]     = s;
          red[row*16 + 8 + wid] = ss;
        }
      }
    }
    __syncthreads();
    if (tid < 32){
      float s = 0.f, ss = 0.f;
      #pragma unroll
      for (int i=0;i<8;++i){ s += red[tid*16 + i]; ss += red[tid*16 + 8 + i]; }
      float mu = s * (1.f/256.f);
      float var = ss * (1.f/256.f) - mu*mu;
      st[tid*2]   = mu;
      st[tid*2+1] = rsqrtf(var + 1e-5f);
    }
    __syncthreads();
  }

  #pragma unroll
  for (int mb=0;mb<2;++mb){
    #pragma unroll
    for (int r=0;r<4;++r){
      int row = mb*16 + hi4*4 + r;
      float mu = 0.f, rs = 1.f;
      if (do_ln){ mu = st[row*2]; rs = st[row*2+1]; }
      #pragma unroll
      for (int nb=0;nb<2;++nb){
        int c = n0 + nb*16 + lo16;
        float v = acc[mb][nb][r];
        if (do_ln) v = (v - mu) * rs * gv[nb] + bbv[nb];
        if (do_relu) v = fmaxf(v, 0.f);
        out[(b0 + row)*256 + c] = v;
      }
    }
  }
}

// ---------------------------------------------------------------------------
__global__ __launch_bounds__(256)
void k3_softmax(const float* __restrict__ scores, float* __restrict__ wts)
{
  const int b = blockIdx.x, t = threadIdx.x;
  const int wid = t >> 6, lane = t & 63;
  __shared__ float r4[4];
  float sc[4];
  #pragma unroll
  for (int n=0;n<4;++n) sc[n] = scores[(b*4 + n)*256 + t];
  float wsum = 0.f;
  for (int n=0;n<4;++n){
    float m = sc[n];
    #pragma unroll
    for (int k=1;k<64;k<<=1) m = fmaxf(m, __shfl_xor(m, k, 64));
    if (lane == 0) r4[wid] = m;
    __syncthreads();
    m = fmaxf(fmaxf(r4[0], r4[1]), fmaxf(r4[2], r4[3]));
    __syncthreads();
    float ex = __expf(sc[n] - m);
    float s = ex;
    #pragma unroll
    for (int k=1;k<64;k<<=1) s += __shfl_xor(s, k, 64);
    if (lane == 0) r4[wid] = s;
    __syncthreads();
    s = r4[0] + r4[1] + r4[2] + r4[3];
    __syncthreads();
    wsum += ex / s;
  }
  wts[b*256 + t] = wsum * 0.25f;
}

// ---------------------------------------------------------------------------
// k4a: reference's literal einsum 'beh,eh->bh' with weights shape (B,E):
//   combined[b,h] = sum_e eo[b,e,h] * wts_flat[e*256 + h]
// block 1024: 4 e-chunks in parallel, LDS reduce.
// ---------------------------------------------------------------------------
__global__ __launch_bounds__(1024)
void k4a_combined(const float* __restrict__ eo, const float* __restrict__ wts,
                  float* __restrict__ cmb)
{
  __shared__ float part[1024];
  const int b = blockIdx.x, t = threadIdx.x;
  const int c = t >> 8, h = t & 255;
  const float* p = eo + b*65536 + h;
  float s = 0.f;
  #pragma unroll 8
  for (int i = 0; i < 64; ++i){
    int e2 = c*64 + i;
    s += p[e2*256] * wts[e2*256 + h];
  }
  part[t] = s;
  __syncthreads();
  if (t < 256) cmb[b*256 + t] = part[t] + part[t+256] + part[t+512] + part[t+768];
}

extern "C" void kernel_launch(void* const* d_in, const int* in_sizes, int n_in,
                              void* d_out, int out_size, void* d_ws, size_t ws_size,
                              hipStream_t stream)
{
  const float* x    = (const float*)d_in[0];
  const float* te   = (const float*)d_in[1];
  const float* W1   = (const float*)d_in[2];
  const float* b1   = (const float*)d_in[3];
  const float* g1   = (const float*)d_in[4];
  const float* bb1  = (const float*)d_in[5];
  const float* W2   = (const float*)d_in[6];
  const float* b2   = (const float*)d_in[7];
  const float* ipw  = (const float*)d_in[8];
  const float* ipb  = (const float*)d_in[9];
  const float* cw   = (const float*)d_in[10];
  const float* cb   = (const float*)d_in[11];
  const float* cg   = (const float*)d_in[12];
  const float* cbt  = (const float*)d_in[13];

  float* out    = (float*)d_out;        // (256,256)
  float* wts    = out + 65536;          // (256,1,256)
  float* eo     = out + 131072;         // (256,256,256)

  // ws layout (f16-W path): w1h | w2h | wkh | q | scores | cmb
  const size_t F16_BYTES = 2ull*(16777216ull*2 + 65536);   // 67239936
  const size_t NEED = F16_BYTES + 4ull*(65536 + 262144 + 65536); // 68812800
  const bool f16w = ws_size >= NEED;

  f16_t* w1h = (f16_t*)d_ws;
  f16_t* w2h = w1h + 16777216;
  f16_t* wkh = w2h + 16777216;
  float* fbase = f16w ? (float*)((char*)d_ws + F16_BYTES) : (float*)d_ws;
  float* q      = fbase;
  float* scores = q + 65536;
  float* cmb    = scores + 262144;

  // q = (te @ Wq^T + bq) / 8
  k_mini<<<8, 512, 0, stream>>>(te, ipw, ipb, 0.125f, 0, nullptr, nullptr, 0, q);

  if (f16w){
    k0_cvt<<<2048, 256, 0, stream>>>(W1, W2, ipw + 65536, w1h, w2h, wkh);
    k2_fused<1><<<1024, 512, 0, stream>>>(x, w1h, b1, g1, bb1, w2h, b2,
                                          wkh, ipb, q, eo, scores);
  } else {
    k2_fused<0><<<1024, 512, 0, stream>>>(x, W1, b1, g1, bb1, W2, b2,
                                          ipw + 65536, ipb, q, eo, scores);
  }

  // softmax over experts, mean over heads -> weights (out)
  k3_softmax<<<256, 256, 0, stream>>>(scores, wts);
  // combined[b,h] = sum_e eo[b,e,h] * wts[e,h]
  k4a_combined<<<256, 1024, 0, stream>>>(eo, wts, cmb);
  // out = relu(LN(combined @ cw^T + cb))
  k_mini<<<8, 512, 0, stream>>>(cmb, cw, cb, 1.0f, 1, cg, cbt, 1, out);
}

// Round 8
// 143.605 us; speedup vs baseline: 1.6822x; 1.0330x over previous
//
#include <hip/hip_runtime.h>

typedef _Float16 f16_t;
typedef f16_t f16x8 __attribute__((ext_vector_type(8)));
typedef float f32x4 __attribute__((ext_vector_type(4)));

#define MFMA16(a,b,c) __builtin_amdgcn_mfma_f32_16x16x32_f16(a,b,c,0,0,0)
#define VM0 asm volatile("s_waitcnt vmcnt(0)" ::: "memory")
#define VM2 asm volatile("s_waitcnt vmcnt(2)" ::: "memory")

// async global -> LDS, 16B per lane. LDS dest is wave-uniform base + lane*16
// (we pass base + lane*16; HW uses first lane's base). Global src is per-lane.
__device__ __forceinline__ void cp16(const void* g, void* l){
  __builtin_amdgcn_global_load_lds(
      (const __attribute__((address_space(1))) void*)g,
      (__attribute__((address_space(3))) void*)l, 16, 0, 0);
}

__device__ __forceinline__ f16x8 cvt8h(float4 a, float4 b){
  f16x8 r;
  r[0]=(f16_t)a.x; r[1]=(f16_t)a.y; r[2]=(f16_t)a.z; r[3]=(f16_t)a.w;
  r[4]=(f16_t)b.x; r[5]=(f16_t)b.y; r[6]=(f16_t)b.z; r[7]=(f16_t)b.w;
  return r;
}

// Stage rows x 256 f32 (row-major) -> LDS f16 [row][256], per-row XOR swizzle
// on 16B chunks: chunk' = chunk ^ (row&7). Row pitch 512B.
template<int NT>
__device__ __forceinline__ void stage_f16(const float* __restrict__ src,
                                          char* dst, int rows, int tid){
  const int nchunk = rows * 32;
  const float4* s4 = reinterpret_cast<const float4*>(src);
  for (int cid = tid; cid < nchunk; cid += NT){
    int r = cid >> 5, c = cid & 31;
    *reinterpret_cast<f16x8*>(dst + r*512 + ((c ^ (r&7))<<4)) = cvt8h(s4[cid*2], s4[cid*2+1]);
  }
}

__device__ __forceinline__ f16x8 ldsA(const char* buf, int row, int c16){
  return *reinterpret_cast<const f16x8*>(buf + row*512 + ((c16 ^ (row&7))<<4));
}

// ---- wave-private W pipeline --------------------------------------------
// Each wave owns rows n0..n0+31 of W (f16, 256 cols). Per K-step (kb) its
// slice is 32 rows x 32 k = 2KB, staged as 2 x 1KB gload_lds issues into a
// 2-slot ring. LDS tile layout (linear, matches gload_lds lane order):
//   slot*2048 + j*1024 + lane*16  <=  W[(n0 + j*16 + lane/4)*256 + kb*32 + (lane%4)*8]
// Read for (row = nb*16+lo16, k-chunk hi4): nb*1024 + lo16*64 + hi4*16
// (b128 bank histogram is uniform -> no swizzle needed).
__device__ __forceinline__ void issue_tile(const f16_t* wsrc, int kb, char* wt, int lane){
  const f16_t* s = wsrc + kb*32;
  char* d = wt + (kb&1)*2048 + lane*16;
  cp16(s, d);
  cp16(s + 16*256, d + 1024);
}

// 64x32 C tile, K=256, software-pipelined: consume tile kb (vmcnt(2): tile
// kb+1 stays in flight), then issue tile kb+2 into the slot kb just freed.
__device__ __forceinline__ void gemm_pipe(f32x4 acc[4][2], const char* bufA,
    const f16_t* wsrc, char* wt, int lane, int lo16, int hi4){
  #pragma unroll
  for (int kb = 0; kb < 8; ++kb){
    if (kb < 7) { VM2; } else { VM0; }
    const char* ws = wt + (kb&1)*2048 + lo16*64 + hi4*16;
    f16x8 bf0 = *reinterpret_cast<const f16x8*>(ws);
    f16x8 bf1 = *reinterpret_cast<const f16x8*>(ws + 1024);
    #pragma unroll
    for (int mb = 0; mb < 4; ++mb){
      f16x8 af = ldsA(bufA, mb*16 + lo16, kb*4 + hi4);
      acc[mb][0] = MFMA16(af, bf0, acc[mb][0]);
      acc[mb][1] = MFMA16(af, bf1, acc[mb][1]);
    }
    __builtin_amdgcn_sched_barrier(0);   // keep the refill below the reads above
    if (kb + 2 < 8) issue_tile(wsrc, kb + 2, wt, lane);
  }
}

// f32-W streaming fallback (only used when ws_size can't hold f16 weights)
__device__ __forceinline__ void gemm_w32(f32x4 acc[4][2], const char* bufA,
    const float* __restrict__ W, int n0, int lo16, int hi4){
  #pragma unroll
  for (int kb = 0; kb < 8; ++kb){
    f16x8 bf[2];
    #pragma unroll
    for (int nb = 0; nb < 2; ++nb){
      const float4* p = reinterpret_cast<const float4*>(W + ((n0 + nb*16 + lo16)<<8) + kb*32 + hi4*8);
      bf[nb] = cvt8h(p[0], p[1]);
    }
    #pragma unroll
    for (int mb = 0; mb < 4; ++mb){
      f16x8 af = ldsA(bufA, mb*16 + lo16, kb*4 + hi4);
      acc[mb][0] = MFMA16(af, bf[0], acc[mb][0]);
      acc[mb][1] = MFMA16(af, bf[1], acc[mb][1]);
    }
  }
}

// ---------------------------------------------------------------------------
// k0_cvt: one-shot f32 -> f16 conversion of W1, W2, Wk into d_ws.
// ---------------------------------------------------------------------------
__global__ __launch_bounds__(256)
void k0_cvt(const float* __restrict__ W1, const float* __restrict__ W2,
            const float* __restrict__ Wk, f16_t* __restrict__ w1h,
            f16_t* __restrict__ w2h, f16_t* __restrict__ wkh)
{
  const long long NG1 = 2097152, NG2 = 4194304, NGT = 4202496; // 8-elem groups
  for (long long gidx = (long long)blockIdx.x*256 + threadIdx.x; gidx < NGT;
       gidx += (long long)gridDim.x*256){
    const float4* s; f16_t* d; long long off;
    if (gidx < NG1){ s = (const float4*)W1; d = w1h; off = gidx; }
    else if (gidx < NG2){ s = (const float4*)W2; d = w2h; off = gidx - NG1; }
    else { s = (const float4*)Wk; d = wkh; off = gidx - NG2; }
    *reinterpret_cast<f16x8*>(d + off*8) = cvt8h(s[off*2], s[off*2+1]);
  }
}

// ---------------------------------------------------------------------------
// k2_fused: per (expert e, 64-row batch tile):
//   h = x@W1[e]^T + b1 ; LN ; relu -> hr(f16 LDS) ; eo = hr@W2[e]^T + b2 ->
//   global f32 + f16 LDS ; k = eo@Wk^T + bk ; scores[b,hd,e] = q . k
// grid 1024 XCD-swizzled; block 512 = 8 col-waves. W delivered via the
// wave-private async LDS pipe; prologue of GEMM g+1 issued before the
// preceding barrier phase so its latency hides under LN / eo-store work.
// ---------------------------------------------------------------------------
template<int W16>
__global__ __launch_bounds__(512, 4)
void k2_fused(const float* __restrict__ x, const void* __restrict__ W1v,
              const float* __restrict__ b1, const float* __restrict__ g1,
              const float* __restrict__ bb1, const void* __restrict__ W2v,
              const float* __restrict__ b2, const void* __restrict__ Wkv,
              const float* __restrict__ ipb, const float* __restrict__ q,
              float* __restrict__ eo_out, float* __restrict__ scores)
{
  __shared__ __align__(16) char lds[70144];
  char* bufA = lds;                    // 32KB: x(f16) -> hr(f16) -> eo(f16)
  float* red = (float*)(lds + 32768);  // [64][16] = 4KB
  float* st  = (float*)(lds + 36864);  // [64][2]  = 512B
  char* wpipe = lds + 37376;           // 8 waves x 2 slots x 2KB = 32KB

  const int l = blockIdx.x;
  const int e    = (l & 7) * 32 + (l >> 5);
  const int b0   = ((l >> 3) & 3) * 64;
  const int tid = threadIdx.x;
  const int lane = tid & 63, wid = tid >> 6;
  const int lo16 = lane & 15, hi4 = lane >> 4;
  const int n0 = wid * 32;
  char* wt = wpipe + wid*4096;

  const int r_in = lane >> 2, c_in = (lane & 3) * 8;
  const f16_t* src1 = nullptr; const f16_t* src2 = nullptr; const f16_t* srcK = nullptr;
  if (W16){
    src1 = (const f16_t*)W1v + e*65536 + (n0 + r_in)*256 + c_in;
    src2 = (const f16_t*)W2v + e*65536 + (n0 + r_in)*256 + c_in;
    srcK = (const f16_t*)Wkv +           (n0 + r_in)*256 + c_in;
    issue_tile(src1, 0, wt, lane);       // G1 prefetch hides under x-stage
    issue_tile(src1, 1, wt, lane);
  }

  stage_f16<512>(x + b0*256, bufA, 64, tid);
  __syncthreads();

  f32x4 acc[4][2];
  #pragma unroll
  for (int mb=0;mb<4;++mb){
    #pragma unroll
    for (int nb=0;nb<2;++nb) acc[mb][nb] = (f32x4)0.0f;
  }

  if (W16) gemm_pipe(acc, bufA, src1, wt, lane, lo16, hi4);
  else     gemm_w32(acc, bufA, (const float*)W1v + e*65536, n0, lo16, hi4);

  if (W16){                              // G2 prefetch hides under LN phase
    issue_tile(src2, 0, wt, lane);
    issue_tile(src2, 1, wt, lane);
  }

  float b1v[2], g1v[2], bbv[2];
  #pragma unroll
  for (int nb=0;nb<2;++nb){
    int c = n0 + nb*16 + lo16;
    b1v[nb] = b1[e*256 + c];
    g1v[nb] = g1[e*256 + c];
    bbv[nb] = bb1[e*256 + c];
  }
  #pragma unroll
  for (int mb=0;mb<4;++mb){
    #pragma unroll
    for (int nb=0;nb<2;++nb){
      #pragma unroll
      for (int r=0;r<4;++r) acc[mb][nb][r] += b1v[nb];
    }
  }

  // LN stats: per-row sum/sumsq across the 8 column-waves
  #pragma unroll
  for (int mb=0;mb<4;++mb){
    #pragma unroll
    for (int r=0;r<4;++r){
      float s=0.f, ss=0.f;
      #pragma unroll
      for (int nb=0;nb<2;++nb){ float v = acc[mb][nb][r]; s += v; ss += v*v; }
      #pragma unroll
      for (int m=1;m<16;m<<=1){ s += __shfl_xor(s, m, 64); ss += __shfl_xor(ss, m, 64); }
      if (lo16 == 0){
        int row = mb*16 + hi4*4 + r;
        red[row*16 + wid]     = s;
        red[row*16 + 8 + wid] = ss;
      }
    }
  }
  __syncthreads();   // also: all waves done reading x from bufA
  if (tid < 64){
    float s  = 0.f, ss = 0.f;
    #pragma unroll
    for (int i=0;i<8;++i){ s += red[tid*16 + i]; ss += red[tid*16 + 8 + i]; }
    float mu = s * (1.f/256.f);
    float var = ss * (1.f/256.f) - mu*mu;
    st[tid*2]   = mu;
    st[tid*2+1] = rsqrtf(var + 1e-5f);
  }
  __syncthreads();

  // LN + relu -> hr (f16) back into bufA
  #pragma unroll
  for (int mb=0;mb<4;++mb){
    #pragma unroll
    for (int r=0;r<4;++r){
      int row = mb*16 + hi4*4 + r;
      float mu = st[row*2], rs = st[row*2+1];
      #pragma unroll
      for (int nb=0;nb<2;++nb){
        int c = n0 + nb*16 + lo16;
        float v = (acc[mb][nb][r] - mu) * rs * g1v[nb] + bbv[nb];
        v = fmaxf(v, 0.f);
        int off = row*512 + (((c>>3) ^ (row&7))<<4) + (c&7)*2;
        *reinterpret_cast<f16_t*>(bufA + off) = (f16_t)v;
      }
    }
  }
  __syncthreads();

  // GEMM2: eo = hr @ W2[e]^T + b2
  #pragma unroll
  for (int mb=0;mb<4;++mb){
    #pragma unroll
    for (int nb=0;nb<2;++nb) acc[mb][nb] = (f32x4)0.0f;
  }
  if (W16) gemm_pipe(acc, bufA, src2, wt, lane, lo16, hi4);
  else     gemm_w32(acc, bufA, (const float*)W2v + e*65536, n0, lo16, hi4);

  float b2v[2];
  #pragma unroll
  for (int nb=0;nb<2;++nb) b2v[nb] = b2[e*256 + n0 + nb*16 + lo16];

  __syncthreads();  // all waves done reading hr before eo overwrites bufA

  if (W16){                              // G3 prefetch hides under eo stores
    issue_tile(srcK, 0, wt, lane);
    issue_tile(srcK, 1, wt, lane);
  }

  #pragma unroll
  for (int mb=0;mb<4;++mb){
    #pragma unroll
    for (int r=0;r<4;++r){
      int row = mb*16 + hi4*4 + r;
      int b = b0 + row;
      #pragma unroll
      for (int nb=0;nb<2;++nb){
        int c = n0 + nb*16 + lo16;
        float v = acc[mb][nb][r] + b2v[nb];
        eo_out[(b*256 + e)*256 + c] = v;
        int off = row*512 + (((c>>3) ^ (row&7))<<4) + (c&7)*2;
        *reinterpret_cast<f16_t*>(bufA + off) = (f16_t)v;
      }
    }
  }
  __syncthreads();

  // GEMM3: k = eo @ Wk^T + bk ; scores = q . k
  #pragma unroll
  for (int mb=0;mb<4;++mb){
    #pragma unroll
    for (int nb=0;nb<2;++nb) acc[mb][nb] = (f32x4)0.0f;
  }
  if (W16) gemm_pipe(acc, bufA, srcK, wt, lane, lo16, hi4);
  else     gemm_w32(acc, bufA, (const float*)Wkv, n0, lo16, hi4);

  float bkv[2];
  #pragma unroll
  for (int nb=0;nb<2;++nb) bkv[nb] = ipb[256 + n0 + nb*16 + lo16];

  #pragma unroll
  for (int mb=0;mb<4;++mb){
    #pragma unroll
    for (int r=0;r<4;++r){
      int row = mb*16 + hi4*4 + r;
      int b = b0 + row;
      float p = 0.f;
      #pragma unroll
      for (int nb=0;nb<2;++nb){
        int c = n0 + nb*16 + lo16;
        p += q[b*256 + c] * (acc[mb][nb][r] + bkv[nb]);
      }
      #pragma unroll
      for (int m=1;m<16;m<<=1) p += __shfl_xor(p, m, 64);
      if (lo16 == 0) red[row*16 + wid] = p;   // partial over this wave's 32 cols
    }
  }
  __syncthreads();
  if (tid < 256){
    int row = tid >> 2, hd = tid & 3;
    float sc = red[row*16 + hd*2] + red[row*16 + hd*2 + 1];
    scores[((b0 + row)*4 + hd)*256 + e] = sc;
  }
}

// ---------------------------------------------------------------------------
// k_mini: out = act( maybeLN( (A @ W^T + bias) * scale ) ), 256x256x256, f16.
// grid 8 (32-row tiles), block 512 = 8 col-waves, acc[2][2].
// ---------------------------------------------------------------------------
__global__ __launch_bounds__(512, 4)
void k_mini(const float* __restrict__ A, const float* __restrict__ W,
            const float* __restrict__ bias, float scale, int do_ln,
            const float* __restrict__ g, const float* __restrict__ bb,
            int do_relu, float* __restrict__ out)
{
  __shared__ __align__(16) char lds[18688];
  char* bufA = lds;                    // 16KB: A rows (f16)
  float* red = (float*)(lds + 16384);  // [32][16] = 2KB
  float* st  = (float*)(lds + 18432);  // [32][2]  = 256B

  const int b0 = blockIdx.x * 32;
  const int tid = threadIdx.x;
  const int lane = tid & 63, wid = tid >> 6;
  const int lo16 = lane & 15, hi4 = lane >> 4;
  const int n0 = wid * 32;

  stage_f16<512>(A + b0*256, bufA, 32, tid);
  __syncthreads();

  f32x4 acc[2][2];
  #pragma unroll
  for (int mb=0;mb<2;++mb){
    #pragma unroll
    for (int nb=0;nb<2;++nb) acc[mb][nb] = (f32x4)0.0f;
  }
  #pragma unroll
  for (int kb = 0; kb < 8; ++kb){
    f16x8 bf[2];
    #pragma unroll
    for (int nb = 0; nb < 2; ++nb){
      const float4* p = reinterpret_cast<const float4*>(W + ((n0 + nb*16 + lo16)<<8) + kb*32 + hi4*8);
      bf[nb] = cvt8h(p[0], p[1]);
    }
    #pragma unroll
    for (int mb = 0; mb < 2; ++mb){
      f16x8 af = ldsA(bufA, mb*16 + lo16, kb*4 + hi4);
      acc[mb][0] = MFMA16(af, bf[0], acc[mb][0]);
      acc[mb][1] = MFMA16(af, bf[1], acc[mb][1]);
    }
  }

  float bv[2], gv[2], bbv[2];
  #pragma unroll
  for (int nb=0;nb<2;++nb){
    int c = n0 + nb*16 + lo16;
    bv[nb]  = bias[c];
    gv[nb]  = do_ln ? g[c]  : 1.f;
    bbv[nb] = do_ln ? bb[c] : 0.f;
  }
  #pragma unroll
  for (int mb=0;mb<2;++mb){
    #pragma unroll
    for (int nb=0;nb<2;++nb){
      #pragma unroll
      for (int r=0;r<4;++r) acc[mb][nb][r] = (acc[mb][nb][r] + bv[nb]) * scale;
    }
  }

  if (do_ln){
    #pragma unroll
    for (int mb=0;mb<2;++mb){
      #pragma unroll
      for (int r=0;r<4;++r){
        float s=0.f, ss=0.f;
        #pragma unroll
        for (int nb=0;nb<2;++nb){ float v = acc[mb][nb][r]; s += v; ss += v*v; }
        #pragma unroll
        for (int m=1;m<16;m<<=1){ s += __shfl_xor(s, m, 64); ss += __shfl_xor(ss, m, 64); }
        if (lo16 == 0){
          int row = mb*16 + hi4*4 + r;
          red[row*16 + wid]     = s;
          red[row*16 + 8 + wid] = ss;
        }
      }
    }
    __syncthreads();
    if (tid < 32){
      float s = 0.f, ss = 0.f;
      #pragma unroll
      for (int i=0;i<8;++i){ s += red[tid*16 + i]; ss += red[tid*16 + 8 + i]; }
      float mu = s * (1.f/256.f);
      float var = ss * (1.f/256.f) - mu*mu;
      st[tid*2]   = mu;
      st[tid*2+1] = rsqrtf(var + 1e-5f);
    }
    __syncthreads();
  }

  #pragma unroll
  for (int mb=0;mb<2;++mb){
    #pragma unroll
    for (int r=0;r<4;++r){
      int row = mb*16 + hi4*4 + r;
      float mu = 0.f, rs = 1.f;
      if (do_ln){ mu = st[row*2]; rs = st[row*2+1]; }
      #pragma unroll
      for (int nb=0;nb<2;++nb){
        int c = n0 + nb*16 + lo16;
        float v = acc[mb][nb][r];
        if (do_ln) v = (v - mu) * rs * gv[nb] + bbv[nb];
        if (do_relu) v = fmaxf(v, 0.f);
        out[(b0 + row)*256 + c] = v;
      }
    }
  }
}

// ---------------------------------------------------------------------------
__global__ __launch_bounds__(256)
void k3_softmax(const float* __restrict__ scores, float* __restrict__ wts)
{
  const int b = blockIdx.x, t = threadIdx.x;
  const int wid = t >> 6, lane = t & 63;
  __shared__ float r4[4];
  float sc[4];
  #pragma unroll
  for (int n=0;n<4;++n) sc[n] = scores[(b*4 + n)*256 + t];
  float wsum = 0.f;
  for (int n=0;n<4;++n){
    float m = sc[n];
    #pragma unroll
    for (int k=1;k<64;k<<=1) m = fmaxf(m, __shfl_xor(m, k, 64));
    if (lane == 0) r4[wid] = m;
    __syncthreads();
    m = fmaxf(fmaxf(r4[0], r4[1]), fmaxf(r4[2], r4[3]));
    __syncthreads();
    float ex = __expf(sc[n] - m);
    float s = ex;
    #pragma unroll
    for (int k=1;k<64;k<<=1) s += __shfl_xor(s, k, 64);
    if (lane == 0) r4[wid] = s;
    __syncthreads();
    s = r4[0] + r4[1] + r4[2] + r4[3];
    __syncthreads();
    wsum += ex / s;
  }
  wts[b*256 + t] = wsum * 0.25f;
}

// ---------------------------------------------------------------------------
// k4a: reference's literal einsum 'beh,eh->bh' with weights shape (B,E):
//   combined[b,h] = sum_e eo[b,e,h] * wts_flat[e*256 + h]
// block 1024: 4 e-chunks in parallel, LDS reduce.
// ---------------------------------------------------------------------------
__global__ __launch_bounds__(1024)
void k4a_combined(const float* __restrict__ eo, const float* __restrict__ wts,
                  float* __restrict__ cmb)
{
  __shared__ float part[1024];
  const int b = blockIdx.x, t = threadIdx.x;
  const int c = t >> 8, h = t & 255;
  const float* p = eo + b*65536 + h;
  float s = 0.f;
  #pragma unroll 8
  for (int i = 0; i < 64; ++i){
    int e2 = c*64 + i;
    s += p[e2*256] * wts[e2*256 + h];
  }
  part[t] = s;
  __syncthreads();
  if (t < 256) cmb[b*256 + t] = part[t] + part[t+256] + part[t+512] + part[t+768];
}

extern "C" void kernel_launch(void* const* d_in, const int* in_sizes, int n_in,
                              void* d_out, int out_size, void* d_ws, size_t ws_size,
                              hipStream_t stream)
{
  const float* x    = (const float*)d_in[0];
  const float* te   = (const float*)d_in[1];
  const float* W1   = (const float*)d_in[2];
  const float* b1   = (const float*)d_in[3];
  const float* g1   = (const float*)d_in[4];
  const float* bb1  = (const float*)d_in[5];
  const float* W2   = (const float*)d_in[6];
  const float* b2   = (const float*)d_in[7];
  const float* ipw  = (const float*)d_in[8];
  const float* ipb  = (const float*)d_in[9];
  const float* cw   = (const float*)d_in[10];
  const float* cb   = (const float*)d_in[11];
  const float* cg   = (const float*)d_in[12];
  const float* cbt  = (const float*)d_in[13];

  float* out    = (float*)d_out;        // (256,256)
  float* wts    = out + 65536;          // (256,1,256)
  float* eo     = out + 131072;         // (256,256,256)

  // ws layout (f16-W path): w1h | w2h | wkh | q | scores | cmb
  const size_t F16_BYTES = 2ull*(16777216ull*2 + 65536);   // 67239936
  const size_t NEED = F16_BYTES + 4ull*(65536 + 262144 + 65536); // 68812800
  const bool f16w = ws_size >= NEED;

  f16_t* w1h = (f16_t*)d_ws;
  f16_t* w2h = w1h + 16777216;
  f16_t* wkh = w2h + 16777216;
  float* fbase = f16w ? (float*)((char*)d_ws + F16_BYTES) : (float*)d_ws;
  float* q      = fbase;
  float* scores = q + 65536;
  float* cmb    = scores + 262144;

  // q = (te @ Wq^T + bq) / 8
  k_mini<<<8, 512, 0, stream>>>(te, ipw, ipb, 0.125f, 0, nullptr, nullptr, 0, q);

  if (f16w){
    k0_cvt<<<2048, 256, 0, stream>>>(W1, W2, ipw + 65536, w1h, w2h, wkh);
    k2_fused<1><<<1024, 512, 0, stream>>>(x, w1h, b1, g1, bb1, w2h, b2,
                                          wkh, ipb, q, eo, scores);
  } else {
    k2_fused<0><<<1024, 512, 0, stream>>>(x, W1, b1, g1, bb1, W2, b2,
                                          ipw + 65536, ipb, q, eo, scores);
  }

  // softmax over experts, mean over heads -> weights (out)
  k3_softmax<<<256, 256, 0, stream>>>(scores, wts);
  // combined[b,h] = sum_e eo[b,e,h] * wts[e,h]
  k4a_combined<<<256, 1024, 0, stream>>>(eo, wts, cmb);
  // out = relu(LN(combined @ cw^T + cb))
  k_mini<<<8, 512, 0, stream>>>(cmb, cw, cb, 1.0f, 1, cg, cbt, 1, out);
}